// Round 1
// baseline (636.291 us; speedup 1.0000x reference)
//
#include <hip/hip_runtime.h>
#include <math.h>

#define NEG_SLOPE 0.2f
#define HC 256      // heads * per-head channels
#define CAPD 128    // LDS stash capacity per wave (degree cap; fallback recomputes)

static __device__ __forceinline__ float wave_max(float v) {
#pragma unroll
  for (int off = 32; off; off >>= 1) v = fmaxf(v, __shfl_xor(v, off));
  return v;
}
static __device__ __forceinline__ float wave_sum(float v) {
#pragma unroll
  for (int off = 32; off; off >>= 1) v += __shfl_xor(v, off);
  return v;
}

// ---- detect int64 vs int32 edge_index: odd dwords all zero <=> int64 ----
__global__ void k_detect(const int* __restrict__ ei, int* __restrict__ flag) {
  int lane = threadIdx.x;
  int v = ei[2 * lane + 1];
#pragma unroll
  for (int off = 32; off; off >>= 1) v |= __shfl_xor(v, off);
  if (lane == 0) *flag = (v == 0) ? 1 : 0;
}

// ---- degree histogram over E edges + N self loops ----
__global__ void k_hist(const int* __restrict__ ei, const int* __restrict__ flag,
                       int* __restrict__ deg, int E_, int n) {
  int t = blockIdx.x * 256 + threadIdx.x;
  int M = E_ + n;
  if (t >= M) return;
  int is64 = *flag;
  int dst;
  if (t < E_) dst = is64 ? ei[2 * (E_ + t)] : ei[E_ + t];
  else dst = t - E_;
  atomicAdd(&deg[dst], 1);
}

// ---- single-block exclusive scan -> rowptr, cursor ----
__global__ void k_scan(const int* __restrict__ deg, int* __restrict__ rowptr,
                       int* __restrict__ cursor, int n) {
  __shared__ int sums[1024];
  int tid = threadIdx.x;
  int chunk = (n + 1023) >> 10;
  int s0 = tid * chunk;
  int s1 = min(s0 + chunk, n);
  int s = 0;
  for (int i = s0; i < s1; ++i) s += deg[i];
  sums[tid] = s;
  __syncthreads();
  for (int off = 1; off < 1024; off <<= 1) {
    int v = (tid >= off) ? sums[tid - off] : 0;
    __syncthreads();
    sums[tid] += v;
    __syncthreads();
  }
  int run = (tid == 0) ? 0 : sums[tid - 1];
  for (int i = s0; i < s1; ++i) {
    rowptr[i] = run;
    cursor[i] = run;
    run += deg[i];
  }
  if (tid == 1023) rowptr[n] = sums[1023];
}

// ---- scatter src into CSR buckets ----
__global__ void k_scatter(const int* __restrict__ ei, const int* __restrict__ flag,
                          int* __restrict__ cursor, int* __restrict__ csr,
                          int E_, int n) {
  int t = blockIdx.x * 256 + threadIdx.x;
  int M = E_ + n;
  if (t >= M) return;
  int is64 = *flag;
  int src, dst;
  if (t < E_) {
    src = is64 ? ei[2 * t] : ei[t];
    dst = is64 ? ei[2 * (E_ + t)] : ei[E_ + t];
  } else {
    src = dst = t - E_;
  }
  int pos = atomicAdd(&cursor[dst], 1);
  csr[pos] = src;
}

// ---- fused GEMM: H[n,256] = A[n,K] @ W[256,K]^T ; per-head alpha dots fused ----
// grid: (ceil(n/64), 4 heads); block 256. Block (bx, h) computes nodes
// bx*64..+63, channels h*64..+63, plus alpha_s/alpha_d for head h (complete,
// since the 64 channels of this block are exactly head h's channels).
#define BK 32
__global__ __launch_bounds__(256) void k_gemm_fused(
    const float* __restrict__ A, const float* __restrict__ W,
    const float* __restrict__ a_src, const float* __restrict__ a_dst,
    float* __restrict__ H, float* __restrict__ as_out, float* __restrict__ ad_out,
    int n, int K) {
  __shared__ float As[BK][68];
  __shared__ float Bs[BK][68];
  const int head = blockIdx.y;
  const int n0 = blockIdx.x * 64;
  const int tid = threadIdx.x;
  const int tx = tid & 15, ty = tid >> 4;
  float c[4][4];
#pragma unroll
  for (int i = 0; i < 4; ++i)
#pragma unroll
    for (int j = 0; j < 4; ++j) c[i][j] = 0.f;

  for (int k0 = 0; k0 < K; k0 += BK) {
#pragma unroll
    for (int l = 0; l < 2; ++l) {
      int f = tid + l * 256;
      int m = f >> 3, kq = f & 7;
      int row = n0 + m;
      float4 a4 = make_float4(0.f, 0.f, 0.f, 0.f);
      if (row < n) a4 = *(const float4*)(A + (size_t)row * K + k0 + kq * 4);
      As[kq * 4 + 0][m] = a4.x; As[kq * 4 + 1][m] = a4.y;
      As[kq * 4 + 2][m] = a4.z; As[kq * 4 + 3][m] = a4.w;
      float4 b4 = *(const float4*)(W + (size_t)(head * 64 + m) * K + k0 + kq * 4);
      Bs[kq * 4 + 0][m] = b4.x; Bs[kq * 4 + 1][m] = b4.y;
      Bs[kq * 4 + 2][m] = b4.z; Bs[kq * 4 + 3][m] = b4.w;
    }
    __syncthreads();
#pragma unroll
    for (int k = 0; k < BK; ++k) {
      float4 av = *(const float4*)&As[k][ty * 4];
      float4 bv = *(const float4*)&Bs[k][tx * 4];
      float a_[4] = {av.x, av.y, av.z, av.w};
      float b_[4] = {bv.x, bv.y, bv.z, bv.w};
#pragma unroll
      for (int i = 0; i < 4; ++i)
#pragma unroll
        for (int j = 0; j < 4; ++j) c[i][j] = fmaf(a_[i], b_[j], c[i][j]);
    }
    __syncthreads();
  }

  float asv[4], adv[4];
#pragma unroll
  for (int j = 0; j < 4; ++j) {
    asv[j] = a_src[head * 64 + tx * 4 + j];
    adv[j] = a_dst[head * 64 + tx * 4 + j];
  }
#pragma unroll
  for (int i = 0; i < 4; ++i) {
    int row = n0 + ty * 4 + i;
    if (row < n) {
      *(float4*)(H + (size_t)row * HC + head * 64 + tx * 4) =
          make_float4(c[i][0], c[i][1], c[i][2], c[i][3]);
      float ps = c[i][0] * asv[0] + c[i][1] * asv[1] + c[i][2] * asv[2] + c[i][3] * asv[3];
      float pd = c[i][0] * adv[0] + c[i][1] * adv[1] + c[i][2] * adv[2] + c[i][3] * adv[3];
#pragma unroll
      for (int off = 1; off < 16; off <<= 1) {
        ps += __shfl_xor(ps, off);
        pd += __shfl_xor(pd, off);
      }
      if (tx == 0) {
        as_out[row * 4 + head] = ps;
        ad_out[row * 4 + head] = pd;
      }
    }
  }
}

// ---- per-destination softmax + aggregation; block = node, wave = head, lane = channel ----
template <bool ELU>
__global__ __launch_bounds__(256) void k_agg(
    const int* __restrict__ rowptr, const int* __restrict__ csr,
    const float* __restrict__ h, const float* __restrict__ as,
    const float* __restrict__ ad, const float* __restrict__ bias,
    float* __restrict__ out, int n) {
  __shared__ float wbuf[4][CAPD];
  __shared__ int sbuf[4][CAPD];
  __shared__ float red[4][64];
  const int node = blockIdx.x;
  const int wv = threadIdx.x >> 6;
  const int lane = threadIdx.x & 63;
  const int r0 = rowptr[node];
  const int d = rowptr[node + 1] - r0;
  const float adh = ad[node * 4 + wv];

  // pass 1: leaky-relu scores, stash, segment max
  float m = -INFINITY;
  for (int i = lane; i < d; i += 64) {
    int s = csr[r0 + i];
    float v = as[s * 4 + wv] + adh;
    v = (v >= 0.f) ? v : NEG_SLOPE * v;
    if (i < CAPD) { sbuf[wv][i] = s; wbuf[wv][i] = v; }
    m = fmaxf(m, v);
  }
  m = wave_max(m);

  // pass 2: exp + denom
  float dsum = 0.f;
  for (int i = lane; i < d; i += 64) {
    float v;
    if (i < CAPD) v = wbuf[wv][i];
    else {
      int s = csr[r0 + i];
      v = as[s * 4 + wv] + adh;
      v = (v >= 0.f) ? v : NEG_SLOPE * v;
    }
    float ex = __expf(v - m);
    if (i < CAPD) wbuf[wv][i] = ex;
    dsum += ex;
  }
  dsum = wave_sum(dsum);
  const float inv = 1.f / (dsum + 1e-16f);

  // pass 3: weighted gather-aggregate (lane = channel)
  float acc = 0.f;
  for (int e = 0; e < d; ++e) {
    int s;
    float w;
    if (e < CAPD) {
      s = sbuf[wv][e];
      w = wbuf[wv][e];
    } else {
      s = csr[r0 + e];
      float v = as[s * 4 + wv] + adh;
      v = (v >= 0.f) ? v : NEG_SLOPE * v;
      w = __expf(v - m);
    }
    acc = fmaf(w * inv, h[(size_t)s * HC + wv * 64 + lane], acc);
  }

  red[wv][lane] = acc;
  __syncthreads();
  if (wv == 0) {
    float o = 0.25f * (red[0][lane] + red[1][lane] + red[2][lane] + red[3][lane]) + bias[lane];
    if (ELU) o = (o > 0.f) ? o : (__expf(o) - 1.f);
    out[(size_t)node * 64 + lane] = o;
  }
}

extern "C" void kernel_launch(void* const* d_in, const int* in_sizes, int n_in,
                              void* d_out, int out_size, void* d_ws, size_t ws_size,
                              hipStream_t stream) {
  const float* x      = (const float*)d_in[0];
  const int*   ei     = (const int*)d_in[1];
  const float* W1     = (const float*)d_in[2];
  const float* a_src1 = (const float*)d_in[3];
  const float* a_dst1 = (const float*)d_in[4];
  const float* b1     = (const float*)d_in[5];
  const float* W2     = (const float*)d_in[6];
  const float* a_src2 = (const float*)d_in[7];
  const float* a_dst2 = (const float*)d_in[8];
  const float* b2     = (const float*)d_in[9];

  const int n  = in_sizes[0] / 128;   // 50000
  const int E_ = in_sizes[1] / 2;     // 800000
  const int M  = E_ + n;

  char* p = (char*)d_ws;
  auto alloc = [&](size_t bytes) -> void* {
    void* r = (void*)p;
    p += (bytes + 255) & ~(size_t)255;
    return r;
  };
  int*   flag   = (int*)alloc(4);
  int*   deg    = (int*)alloc((size_t)n * 4);
  int*   cursor = (int*)alloc((size_t)n * 4);
  int*   rowptr = (int*)alloc(((size_t)n + 1) * 4);
  int*   csr    = (int*)alloc((size_t)M * 4);
  float* hbuf   = (float*)alloc((size_t)n * HC * 4);  // reused for layer1 h and layer2 h
  float* asb    = (float*)alloc((size_t)n * 4 * 4);
  float* adb    = (float*)alloc((size_t)n * 4 * 4);
  float* hmid   = (float*)alloc((size_t)n * 64 * 4);
  float* out    = (float*)d_out;

  hipMemsetAsync(deg, 0, (size_t)n * 4, stream);
  k_detect<<<1, 64, 0, stream>>>(ei, flag);
  k_hist<<<(M + 255) / 256, 256, 0, stream>>>(ei, flag, deg, E_, n);
  k_scan<<<1, 1024, 0, stream>>>(deg, rowptr, cursor, n);
  k_scatter<<<(M + 255) / 256, 256, 0, stream>>>(ei, flag, cursor, csr, E_, n);

  dim3 ggrid((n + 63) / 64, 4);
  // layer 1
  k_gemm_fused<<<ggrid, 256, 0, stream>>>(x, W1, a_src1, a_dst1, hbuf, asb, adb, n, 128);
  k_agg<true><<<n, 256, 0, stream>>>(rowptr, csr, hbuf, asb, adb, b1, hmid, n);
  // layer 2
  k_gemm_fused<<<ggrid, 256, 0, stream>>>(hmid, W2, a_src2, a_dst2, hbuf, asb, adb, n, 64);
  k_agg<false><<<n, 256, 0, stream>>>(rowptr, csr, hbuf, asb, adb, b2, out, n);
}

// Round 3
// 539.127 us; speedup vs baseline: 1.1802x; 1.1802x over previous
//
#include <hip/hip_runtime.h>
#include <math.h>

#define NEG_SLOPE 0.2f
#define HC 256      // heads * per-head channels
#define CAPD 128    // LDS stash capacity per wave (degree cap; fallback path)
#define SCAN_CHUNK 1024

static __device__ __forceinline__ float wave_max(float v) {
#pragma unroll
  for (int off = 32; off; off >>= 1) v = fmaxf(v, __shfl_xor(v, off));
  return v;
}
static __device__ __forceinline__ float wave_sum(float v) {
#pragma unroll
  for (int off = 32; off; off >>= 1) v += __shfl_xor(v, off);
  return v;
}
static __device__ __forceinline__ int wave_sum_i(int v) {
#pragma unroll
  for (int off = 32; off; off >>= 1) v += __shfl_xor(v, off);
  return v;
}

// ---- detect int64 vs int32 edge_index: odd dwords all zero <=> int64 ----
__global__ void k_detect(const int* __restrict__ ei, int* __restrict__ flag) {
  int lane = threadIdx.x;
  int v = ei[2 * lane + 1];
#pragma unroll
  for (int off = 32; off; off >>= 1) v |= __shfl_xor(v, off);
  if (lane == 0) *flag = (v == 0) ? 1 : 0;
}

// ---- degree histogram over E edges + N self loops ----
__global__ void k_hist(const int* __restrict__ ei, const int* __restrict__ flag,
                       int* __restrict__ deg, int E_, int n) {
  int t = blockIdx.x * 256 + threadIdx.x;
  int M = E_ + n;
  if (t >= M) return;
  int is64 = *flag;
  int dst;
  if (t < E_) dst = is64 ? ei[2 * (E_ + t)] : ei[E_ + t];
  else dst = t - E_;
  atomicAdd(&deg[dst], 1);
}

// ---- 3-kernel scan: per-block partial sums ----
__global__ __launch_bounds__(256) void k_scan_part(const int* __restrict__ deg,
                                                   int* __restrict__ partials, int n) {
  __shared__ int red[4];
  int b = blockIdx.x, tid = threadIdx.x;
  int base = b * SCAN_CHUNK + tid * 4;
  int s = 0;
#pragma unroll
  for (int j = 0; j < 4; ++j) {
    int i = base + j;
    if (i < n) s += deg[i];
  }
  s = wave_sum_i(s);
  if ((tid & 63) == 0) red[tid >> 6] = s;
  __syncthreads();
  if (tid == 0) partials[b] = red[0] + red[1] + red[2] + red[3];
}

// ---- scan the (<=256) partials, in place -> exclusive offsets; rowptr[n]=total ----
__global__ void k_scan_mid(int* __restrict__ partials, int* __restrict__ rowptr,
                           int nb, int n) {
  __shared__ int buf[256];
  int tid = threadIdx.x;
  buf[tid] = (tid < nb) ? partials[tid] : 0;
  __syncthreads();
  if (tid == 0) {
    int run = 0;
    for (int i = 0; i < nb; ++i) {
      int v = buf[i];
      buf[i] = run;
      run += v;
    }
    rowptr[n] = run;
  }
  __syncthreads();
  if (tid < nb) partials[tid] = buf[tid];
}

// ---- block-local scan + global offset -> rowptr, cursor ----
__global__ __launch_bounds__(256) void k_scan_final(const int* __restrict__ deg,
                                                    const int* __restrict__ partials,
                                                    int* __restrict__ rowptr,
                                                    int* __restrict__ cursor, int n) {
  __shared__ int tsum[256];
  int b = blockIdx.x, tid = threadIdx.x;
  int base = b * SCAN_CHUNK + tid * 4;
  int v[4];
  int s = 0;
#pragma unroll
  for (int j = 0; j < 4; ++j) {
    int i = base + j;
    v[j] = (i < n) ? deg[i] : 0;
    s += v[j];
  }
  tsum[tid] = s;
  __syncthreads();
  for (int off = 1; off < 256; off <<= 1) {
    int t = (tid >= off) ? tsum[tid - off] : 0;
    __syncthreads();
    tsum[tid] += t;
    __syncthreads();
  }
  int run = partials[b] + ((tid == 0) ? 0 : tsum[tid - 1]);
#pragma unroll
  for (int j = 0; j < 4; ++j) {
    int i = base + j;
    if (i < n) {
      rowptr[i] = run;
      cursor[i] = run;
      run += v[j];
    }
  }
}

// ---- scatter src into CSR buckets ----
__global__ void k_scatter(const int* __restrict__ ei, const int* __restrict__ flag,
                          int* __restrict__ cursor, int* __restrict__ csr,
                          int E_, int n) {
  int t = blockIdx.x * 256 + threadIdx.x;
  int M = E_ + n;
  if (t >= M) return;
  int is64 = *flag;
  int src, dst;
  if (t < E_) {
    src = is64 ? ei[2 * t] : ei[t];
    dst = is64 ? ei[2 * (E_ + t)] : ei[E_ + t];
  } else {
    src = dst = t - E_;
  }
  int pos = atomicAdd(&cursor[dst], 1);
  csr[pos] = src;
}

// ---- fused GEMM: H[n,256] = A[n,K] @ W[256,K]^T ; per-head alpha dots fused ----
// 128x128 tile, 8x8 per thread. grid: (ceil(n/128), 2); blockIdx.y picks cols
// [128*by,128*by+128) = heads {2by, 2by+1}.
#define BK 32
__global__ __launch_bounds__(256, 2) void k_gemm_fused(
    const float* __restrict__ A, const float* __restrict__ W,
    const float* __restrict__ a_src, const float* __restrict__ a_dst,
    float* __restrict__ H, float* __restrict__ as_out, float* __restrict__ ad_out,
    int n, int K) {
  __shared__ float As[BK][132];
  __shared__ float Bs[BK][132];
  const int by = blockIdx.y;
  const int n0 = blockIdx.x * 128;
  const int tid = threadIdx.x;
  const int tx = tid & 15, ty = tid >> 4;
  float c[8][8];
#pragma unroll
  for (int i = 0; i < 8; ++i)
#pragma unroll
    for (int j = 0; j < 8; ++j) c[i][j] = 0.f;

  for (int k0 = 0; k0 < K; k0 += BK) {
#pragma unroll
    for (int l = 0; l < 4; ++l) {
      int f = tid + l * 256;           // 0..1023
      int m = f >> 3, kq = f & 7;      // m: 0..127 row-in-tile, kq: k-quad
      int row = n0 + m;
      float4 a4 = make_float4(0.f, 0.f, 0.f, 0.f);
      if (row < n) a4 = *(const float4*)(A + (size_t)row * K + k0 + kq * 4);
      As[kq * 4 + 0][m] = a4.x; As[kq * 4 + 1][m] = a4.y;
      As[kq * 4 + 2][m] = a4.z; As[kq * 4 + 3][m] = a4.w;
      float4 b4 = *(const float4*)(W + (size_t)(by * 128 + m) * K + k0 + kq * 4);
      Bs[kq * 4 + 0][m] = b4.x; Bs[kq * 4 + 1][m] = b4.y;
      Bs[kq * 4 + 2][m] = b4.z; Bs[kq * 4 + 3][m] = b4.w;
    }
    __syncthreads();
#pragma unroll
    for (int k = 0; k < BK; ++k) {
      float4 a0 = *(const float4*)&As[k][ty * 8];
      float4 a1 = *(const float4*)&As[k][ty * 8 + 4];
      float4 b0 = *(const float4*)&Bs[k][tx * 8];
      float4 b1 = *(const float4*)&Bs[k][tx * 8 + 4];
      float a_[8] = {a0.x, a0.y, a0.z, a0.w, a1.x, a1.y, a1.z, a1.w};
      float b_[8] = {b0.x, b0.y, b0.z, b0.w, b1.x, b1.y, b1.z, b1.w};
#pragma unroll
      for (int i = 0; i < 8; ++i)
#pragma unroll
        for (int j = 0; j < 8; ++j) c[i][j] = fmaf(a_[i], b_[j], c[i][j]);
    }
    __syncthreads();
  }

  const int head = 2 * by + (tx >> 3);
  float asv[8], adv[8];
#pragma unroll
  for (int j = 0; j < 8; ++j) {
    asv[j] = a_src[head * 64 + (tx & 7) * 8 + j];
    adv[j] = a_dst[head * 64 + (tx & 7) * 8 + j];
  }
#pragma unroll
  for (int i = 0; i < 8; ++i) {
    int row = n0 + ty * 8 + i;
    if (row < n) {
      *(float4*)(H + (size_t)row * HC + by * 128 + tx * 8) =
          make_float4(c[i][0], c[i][1], c[i][2], c[i][3]);
      *(float4*)(H + (size_t)row * HC + by * 128 + tx * 8 + 4) =
          make_float4(c[i][4], c[i][5], c[i][6], c[i][7]);
      float ps = 0.f, pd = 0.f;
#pragma unroll
      for (int j = 0; j < 8; ++j) {
        ps = fmaf(c[i][j], asv[j], ps);
        pd = fmaf(c[i][j], adv[j], pd);
      }
#pragma unroll
      for (int off = 1; off < 8; off <<= 1) {
        ps += __shfl_xor(ps, off);
        pd += __shfl_xor(pd, off);
      }
      if ((tx & 7) == 0) {
        as_out[row * 4 + head] = ps;
        ad_out[row * 4 + head] = pd;
      }
    }
  }
}

// ---- per-destination softmax + aggregation; block = node, wave = head ----
template <bool ELU>
__global__ __launch_bounds__(256) void k_agg(
    const int* __restrict__ rowptr, const int* __restrict__ csr,
    const float* __restrict__ h, const float* __restrict__ as,
    const float* __restrict__ ad, const float* __restrict__ bias,
    float* __restrict__ out, int n) {
  __shared__ float wbuf[4][CAPD];
  __shared__ int sbuf[4][CAPD];
  __shared__ float red[4][64];
  const int node = blockIdx.x;
  const int wv = threadIdx.x >> 6;
  const int lane = threadIdx.x & 63;
  const int r0 = rowptr[node];
  const int d = rowptr[node + 1] - r0;
  const float adh = ad[node * 4 + wv];

  // pass 1: leaky-relu scores, stash, segment max
  float m = -INFINITY;
  for (int i = lane; i < d; i += 64) {
    int s = csr[r0 + i];
    float v = as[s * 4 + wv] + adh;
    v = (v >= 0.f) ? v : NEG_SLOPE * v;
    if (i < CAPD) { sbuf[wv][i] = s; wbuf[wv][i] = v; }
    m = fmaxf(m, v);
  }
  m = wave_max(m);

  // pass 2: exp + denom
  float dsum = 0.f;
  for (int i = lane; i < d; i += 64) {
    float v;
    if (i < CAPD) v = wbuf[wv][i];
    else {
      int s = csr[r0 + i];
      v = as[s * 4 + wv] + adh;
      v = (v >= 0.f) ? v : NEG_SLOPE * v;
    }
    float ex = __expf(v - m);
    if (i < CAPD) wbuf[wv][i] = ex;
    dsum += ex;
  }
  dsum = wave_sum(dsum);
  const float inv = 1.f / (dsum + 1e-16f);

  // pass 3: weighted gather-aggregate
  if (d <= CAPD) {
    // vectorized: 4 edges in flight, 16 lanes x float4 channels per edge
    const int esub = lane >> 4;     // which of the 4 concurrent edges
    const int chq = lane & 15;      // channel quad
    const float* hb = h + (size_t)wv * 64 + chq * 4;
    float4 acc = make_float4(0.f, 0.f, 0.f, 0.f);
    for (int e = 0; e < d; e += 4) {
      int ei_ = e + esub;
      if (ei_ < d) {
        int s = sbuf[wv][ei_];
        float w = wbuf[wv][ei_] * inv;
        float4 hv = *(const float4*)(hb + (size_t)s * HC);
        acc.x = fmaf(w, hv.x, acc.x);
        acc.y = fmaf(w, hv.y, acc.y);
        acc.z = fmaf(w, hv.z, acc.z);
        acc.w = fmaf(w, hv.w, acc.w);
      }
    }
#pragma unroll
    for (int off = 16; off < 64; off <<= 1) {
      acc.x += __shfl_xor(acc.x, off);
      acc.y += __shfl_xor(acc.y, off);
      acc.z += __shfl_xor(acc.z, off);
      acc.w += __shfl_xor(acc.w, off);
    }
    if (esub == 0) *(float4*)&red[wv][chq * 4] = acc;
  } else {
    // scalar fallback (rare): lane = channel
    float a = 0.f;
    for (int e = 0; e < d; ++e) {
      int s;
      float w;
      if (e < CAPD) {
        s = sbuf[wv][e];
        w = wbuf[wv][e];
      } else {
        s = csr[r0 + e];
        float v = as[s * 4 + wv] + adh;
        v = (v >= 0.f) ? v : NEG_SLOPE * v;
        w = __expf(v - m);
      }
      a = fmaf(w * inv, h[(size_t)s * HC + wv * 64 + lane], a);
    }
    red[wv][lane] = a;
  }

  __syncthreads();
  if (wv == 0) {
    float o = 0.25f * (red[0][lane] + red[1][lane] + red[2][lane] + red[3][lane]) + bias[lane];
    if (ELU) o = (o > 0.f) ? o : (__expf(o) - 1.f);
    out[(size_t)node * 64 + lane] = o;
  }
}

extern "C" void kernel_launch(void* const* d_in, const int* in_sizes, int n_in,
                              void* d_out, int out_size, void* d_ws, size_t ws_size,
                              hipStream_t stream) {
  const float* x      = (const float*)d_in[0];
  const int*   ei     = (const int*)d_in[1];
  const float* W1     = (const float*)d_in[2];
  const float* a_src1 = (const float*)d_in[3];
  const float* a_dst1 = (const float*)d_in[4];
  const float* b1     = (const float*)d_in[5];
  const float* W2     = (const float*)d_in[6];
  const float* a_src2 = (const float*)d_in[7];
  const float* a_dst2 = (const float*)d_in[8];
  const float* b2     = (const float*)d_in[9];

  const int n  = in_sizes[0] / 128;   // 50000
  const int E_ = in_sizes[1] / 2;     // 800000
  const int M  = E_ + n;
  const int nb = (n + SCAN_CHUNK - 1) / SCAN_CHUNK;

  char* p = (char*)d_ws;
  auto alloc = [&](size_t bytes) -> void* {
    void* r = (void*)p;
    p += (bytes + 255) & ~(size_t)255;
    return r;
  };
  int*   flag     = (int*)alloc(4);
  int*   deg      = (int*)alloc((size_t)n * 4);
  int*   cursor   = (int*)alloc((size_t)n * 4);
  int*   rowptr   = (int*)alloc(((size_t)n + 1) * 4);
  int*   partials = (int*)alloc(1024);
  int*   csr      = (int*)alloc((size_t)M * 4);
  float* hbuf     = (float*)alloc((size_t)n * HC * 4);
  float* asb      = (float*)alloc((size_t)n * 4 * 4);
  float* adb      = (float*)alloc((size_t)n * 4 * 4);
  float* hmid     = (float*)alloc((size_t)n * 64 * 4);
  float* out      = (float*)d_out;

  hipMemsetAsync(deg, 0, (size_t)n * 4, stream);
  k_detect<<<1, 64, 0, stream>>>(ei, flag);
  k_hist<<<(M + 255) / 256, 256, 0, stream>>>(ei, flag, deg, E_, n);
  k_scan_part<<<nb, 256, 0, stream>>>(deg, partials, n);
  k_scan_mid<<<1, 256, 0, stream>>>(partials, rowptr, nb, n);
  k_scan_final<<<nb, 256, 0, stream>>>(deg, partials, rowptr, cursor, n);
  k_scatter<<<(M + 255) / 256, 256, 0, stream>>>(ei, flag, cursor, csr, E_, n);

  dim3 ggrid((n + 127) / 128, 2);
  // layer 1
  k_gemm_fused<<<ggrid, 256, 0, stream>>>(x, W1, a_src1, a_dst1, hbuf, asb, adb, n, 128);
  k_agg<true><<<n, 256, 0, stream>>>(rowptr, csr, hbuf, asb, adb, b1, hmid, n);
  // layer 2
  k_gemm_fused<<<ggrid, 256, 0, stream>>>(hmid, W2, a_src2, a_dst2, hbuf, asb, adb, n, 64);
  k_agg<false><<<n, 256, 0, stream>>>(rowptr, csr, hbuf, asb, adb, b2, out, n);
}

// Round 8
// 531.164 us; speedup vs baseline: 1.1979x; 1.0150x over previous
//
#include <hip/hip_runtime.h>
#include <math.h>

#define NEG_SLOPE 0.2f
#define HC 256      // heads * per-head channels
#define CAPD 128    // LDS stash capacity per node (degree cap; fallback path)
#define SCAN_CHUNK 1024

static __device__ __forceinline__ int wave_sum_i(int v) {
#pragma unroll
  for (int off = 32; off; off >>= 1) v += __shfl_xor(v, off);
  return v;
}

// ---- detect int64 vs int32 edge_index: odd dwords all zero <=> int64 ----
__global__ void k_detect(const int* __restrict__ ei, int* __restrict__ flag) {
  int lane = threadIdx.x;
  int v = ei[2 * lane + 1];
#pragma unroll
  for (int off = 32; off; off >>= 1) v |= __shfl_xor(v, off);
  if (lane == 0) *flag = (v == 0) ? 1 : 0;
}

// ---- degree histogram over E edges + N self loops ----
__global__ void k_hist(const int* __restrict__ ei, const int* __restrict__ flag,
                       int* __restrict__ deg, int E_, int n) {
  int t = blockIdx.x * 256 + threadIdx.x;
  int M = E_ + n;
  if (t >= M) return;
  int is64 = *flag;
  int dst;
  if (t < E_) dst = is64 ? ei[2 * (E_ + t)] : ei[E_ + t];
  else dst = t - E_;
  atomicAdd(&deg[dst], 1);
}

// ---- 3-kernel scan: per-block partial sums ----
__global__ __launch_bounds__(256) void k_scan_part(const int* __restrict__ deg,
                                                   int* __restrict__ partials, int n) {
  __shared__ int red[4];
  int b = blockIdx.x, tid = threadIdx.x;
  int base = b * SCAN_CHUNK + tid * 4;
  int s = 0;
#pragma unroll
  for (int j = 0; j < 4; ++j) {
    int i = base + j;
    if (i < n) s += deg[i];
  }
  s = wave_sum_i(s);
  if ((tid & 63) == 0) red[tid >> 6] = s;
  __syncthreads();
  if (tid == 0) partials[b] = red[0] + red[1] + red[2] + red[3];
}

// ---- scan the (<=256) partials, in place -> exclusive offsets; rowptr[n]=total ----
__global__ void k_scan_mid(int* __restrict__ partials, int* __restrict__ rowptr,
                           int nb, int n) {
  __shared__ int buf[256];
  int tid = threadIdx.x;
  buf[tid] = (tid < nb) ? partials[tid] : 0;
  __syncthreads();
  if (tid == 0) {
    int run = 0;
    for (int i = 0; i < nb; ++i) {
      int v = buf[i];
      buf[i] = run;
      run += v;
    }
    rowptr[n] = run;
  }
  __syncthreads();
  if (tid < nb) partials[tid] = buf[tid];
}

// ---- block-local scan + global offset -> rowptr, cursor ----
__global__ __launch_bounds__(256) void k_scan_final(const int* __restrict__ deg,
                                                    const int* __restrict__ partials,
                                                    int* __restrict__ rowptr,
                                                    int* __restrict__ cursor, int n) {
  __shared__ int tsum[256];
  int b = blockIdx.x, tid = threadIdx.x;
  int base = b * SCAN_CHUNK + tid * 4;
  int v[4];
  int s = 0;
#pragma unroll
  for (int j = 0; j < 4; ++j) {
    int i = base + j;
    v[j] = (i < n) ? deg[i] : 0;
    s += v[j];
  }
  tsum[tid] = s;
  __syncthreads();
  for (int off = 1; off < 256; off <<= 1) {
    int t = (tid >= off) ? tsum[tid - off] : 0;
    __syncthreads();
    tsum[tid] += t;
    __syncthreads();
  }
  int run = partials[b] + ((tid == 0) ? 0 : tsum[tid - 1]);
#pragma unroll
  for (int j = 0; j < 4; ++j) {
    int i = base + j;
    if (i < n) {
      rowptr[i] = run;
      cursor[i] = run;
      run += v[j];
    }
  }
}

// ---- scatter src into CSR buckets ----
__global__ void k_scatter(const int* __restrict__ ei, const int* __restrict__ flag,
                          int* __restrict__ cursor, int* __restrict__ csr,
                          int E_, int n) {
  int t = blockIdx.x * 256 + threadIdx.x;
  int M = E_ + n;
  if (t >= M) return;
  int is64 = *flag;
  int src, dst;
  if (t < E_) {
    src = is64 ? ei[2 * t] : ei[t];
    dst = is64 ? ei[2 * (E_ + t)] : ei[E_ + t];
  } else {
    src = dst = t - E_;
  }
  int pos = atomicAdd(&cursor[dst], 1);
  csr[pos] = src;
}

// ---- fused GEMM: H[n,256] = A[n,K] @ W[256,K]^T ; per-head alpha dots fused ----
// 128x128 tile, 8x8 per thread. grid: (ceil(n/128), 2); blockIdx.y picks cols
// [128*by,128*by+128) = heads {2by, 2by+1}.
#define BK 32
__global__ __launch_bounds__(256, 2) void k_gemm_fused(
    const float* __restrict__ A, const float* __restrict__ W,
    const float* __restrict__ a_src, const float* __restrict__ a_dst,
    float* __restrict__ H, float* __restrict__ as_out, float* __restrict__ ad_out,
    int n, int K) {
  __shared__ float As[BK][132];
  __shared__ float Bs[BK][132];
  const int by = blockIdx.y;
  const int n0 = blockIdx.x * 128;
  const int tid = threadIdx.x;
  const int tx = tid & 15, ty = tid >> 4;
  float c[8][8];
#pragma unroll
  for (int i = 0; i < 8; ++i)
#pragma unroll
    for (int j = 0; j < 8; ++j) c[i][j] = 0.f;

  for (int k0 = 0; k0 < K; k0 += BK) {
#pragma unroll
    for (int l = 0; l < 4; ++l) {
      int f = tid + l * 256;           // 0..1023
      int m = f >> 3, kq = f & 7;      // m: row-in-tile, kq: k-quad
      int row = n0 + m;
      float4 a4 = make_float4(0.f, 0.f, 0.f, 0.f);
      if (row < n) a4 = *(const float4*)(A + (size_t)row * K + k0 + kq * 4);
      As[kq * 4 + 0][m] = a4.x; As[kq * 4 + 1][m] = a4.y;
      As[kq * 4 + 2][m] = a4.z; As[kq * 4 + 3][m] = a4.w;
      float4 b4 = *(const float4*)(W + (size_t)(by * 128 + m) * K + k0 + kq * 4);
      Bs[kq * 4 + 0][m] = b4.x; Bs[kq * 4 + 1][m] = b4.y;
      Bs[kq * 4 + 2][m] = b4.z; Bs[kq * 4 + 3][m] = b4.w;
    }
    __syncthreads();
#pragma unroll
    for (int k = 0; k < BK; ++k) {
      float4 a0 = *(const float4*)&As[k][ty * 8];
      float4 a1 = *(const float4*)&As[k][ty * 8 + 4];
      float4 b0 = *(const float4*)&Bs[k][tx * 8];
      float4 b1 = *(const float4*)&Bs[k][tx * 8 + 4];
      float a_[8] = {a0.x, a0.y, a0.z, a0.w, a1.x, a1.y, a1.z, a1.w};
      float b_[8] = {b0.x, b0.y, b0.z, b0.w, b1.x, b1.y, b1.z, b1.w};
#pragma unroll
      for (int i = 0; i < 8; ++i)
#pragma unroll
        for (int j = 0; j < 8; ++j) c[i][j] = fmaf(a_[i], b_[j], c[i][j]);
    }
    __syncthreads();
  }

  const int head = 2 * by + (tx >> 3);
  float asv[8], adv[8];
#pragma unroll
  for (int j = 0; j < 8; ++j) {
    asv[j] = a_src[head * 64 + (tx & 7) * 8 + j];
    adv[j] = a_dst[head * 64 + (tx & 7) * 8 + j];
  }
#pragma unroll
  for (int i = 0; i < 8; ++i) {
    int row = n0 + ty * 8 + i;
    if (row < n) {
      *(float4*)(H + (size_t)row * HC + by * 128 + tx * 8) =
          make_float4(c[i][0], c[i][1], c[i][2], c[i][3]);
      *(float4*)(H + (size_t)row * HC + by * 128 + tx * 8 + 4) =
          make_float4(c[i][4], c[i][5], c[i][6], c[i][7]);
      float ps = 0.f, pd = 0.f;
#pragma unroll
      for (int j = 0; j < 8; ++j) {
        ps = fmaf(c[i][j], asv[j], ps);
        pd = fmaf(c[i][j], adv[j], pd);
      }
#pragma unroll
      for (int off = 1; off < 8; off <<= 1) {
        ps += __shfl_xor(ps, off);
        pd += __shfl_xor(pd, off);
      }
      if ((tx & 7) == 0) {
        as_out[row * 4 + head] = ps;
        ad_out[row * 4 + head] = pd;
      }
    }
  }
}

// ---- per-destination softmax + aggregation; WAVE = node ----
// lane layout: head = lane>>4, li = lane&15 (channel-quad in pass B).
// Pass A: 16 lanes/head score 16 edges in parallel, group shuffle-max.
// Pass B: serial over edges; ONE dwordx4/lane covers the full 1KB h[src] row
//         (all 4 heads); online denom; 2-shuffle head-mean epilogue.
template <bool ELU>
__global__ __launch_bounds__(256) void k_agg(
    const int* __restrict__ rowptr, const int* __restrict__ csr,
    const float* __restrict__ h, const float* __restrict__ as,
    const float* __restrict__ ad, const float* __restrict__ bias,
    float* __restrict__ out, int n) {
  __shared__ int   sbuf[4][CAPD];
  __shared__ float wbuf[4][CAPD][5];   // [slot][edge][head(+pad)] — conflict-free
  const int slot = threadIdx.x >> 6;
  const int lane = threadIdx.x & 63;
  const int head = lane >> 4;
  const int li   = lane & 15;
  const int node = blockIdx.x * 4 + slot;
  if (node >= n) return;
  const int r0 = rowptr[node];
  const int d  = rowptr[node + 1] - r0;
  const float adh = ad[node * 4 + head];
  const bool stash = (d <= CAPD);

  // Pass A: leaky-relu scores + per-head max
  float m = -INFINITY;
  for (int i = li; i < d; i += 16) {
    int s = csr[r0 + i];
    float v = as[s * 4 + head] + adh;
    v = (v >= 0.f) ? v : NEG_SLOPE * v;
    if (stash) {
      wbuf[slot][i][head] = v;
      if (head == 0) sbuf[slot][i] = s;
    }
    m = fmaxf(m, v);
  }
#pragma unroll
  for (int off = 1; off < 16; off <<= 1) m = fmaxf(m, __shfl_xor(m, off));

  // Pass B: online denom + full-row weighted gather
  float4 acc = make_float4(0.f, 0.f, 0.f, 0.f);
  float denom = 0.f;
  const float* hb = h + (size_t)head * 64 + li * 4;
  if (stash) {
    for (int e = 0; e < d; ++e) {
      int s = sbuf[slot][e];
      float w = __expf(wbuf[slot][e][head] - m);
      denom += w;
      float4 hv = *(const float4*)(hb + (size_t)s * HC);
      acc.x = fmaf(w, hv.x, acc.x);
      acc.y = fmaf(w, hv.y, acc.y);
      acc.z = fmaf(w, hv.z, acc.z);
      acc.w = fmaf(w, hv.w, acc.w);
    }
  } else {
    for (int e = 0; e < d; ++e) {
      int s = csr[r0 + e];
      float v = as[s * 4 + head] + adh;
      v = (v >= 0.f) ? v : NEG_SLOPE * v;
      float w = __expf(v - m);
      denom += w;
      float4 hv = *(const float4*)(hb + (size_t)s * HC);
      acc.x = fmaf(w, hv.x, acc.x);
      acc.y = fmaf(w, hv.y, acc.y);
      acc.z = fmaf(w, hv.z, acc.z);
      acc.w = fmaf(w, hv.w, acc.w);
    }
  }
  const float inv = 1.f / (denom + 1e-16f);
  acc.x *= inv; acc.y *= inv; acc.z *= inv; acc.w *= inv;

  // head-mean across the 4 lane groups
#pragma unroll
  for (int off = 16; off < 64; off <<= 1) {
    acc.x += __shfl_xor(acc.x, off);
    acc.y += __shfl_xor(acc.y, off);
    acc.z += __shfl_xor(acc.z, off);
    acc.w += __shfl_xor(acc.w, off);
  }
  if (head == 0) {
    float4 b4 = *(const float4*)(bias + li * 4);
    float4 o;
    o.x = 0.25f * acc.x + b4.x;
    o.y = 0.25f * acc.y + b4.y;
    o.z = 0.25f * acc.z + b4.z;
    o.w = 0.25f * acc.w + b4.w;
    if (ELU) {
      o.x = (o.x > 0.f) ? o.x : (__expf(o.x) - 1.f);
      o.y = (o.y > 0.f) ? o.y : (__expf(o.y) - 1.f);
      o.z = (o.z > 0.f) ? o.z : (__expf(o.z) - 1.f);
      o.w = (o.w > 0.f) ? o.w : (__expf(o.w) - 1.f);
    }
    *(float4*)(out + (size_t)node * 64 + li * 4) = o;
  }
}

extern "C" void kernel_launch(void* const* d_in, const int* in_sizes, int n_in,
                              void* d_out, int out_size, void* d_ws, size_t ws_size,
                              hipStream_t stream) {
  const float* x      = (const float*)d_in[0];
  const int*   ei     = (const int*)d_in[1];
  const float* W1     = (const float*)d_in[2];
  const float* a_src1 = (const float*)d_in[3];
  const float* a_dst1 = (const float*)d_in[4];
  const float* b1     = (const float*)d_in[5];
  const float* W2     = (const float*)d_in[6];
  const float* a_src2 = (const float*)d_in[7];
  const float* a_dst2 = (const float*)d_in[8];
  const float* b2     = (const float*)d_in[9];

  const int n  = in_sizes[0] / 128;   // 50000
  const int E_ = in_sizes[1] / 2;     // 800000
  const int M  = E_ + n;
  const int nb = (n + SCAN_CHUNK - 1) / SCAN_CHUNK;

  char* p = (char*)d_ws;
  auto alloc = [&](size_t bytes) -> void* {
    void* r = (void*)p;
    p += (bytes + 255) & ~(size_t)255;
    return r;
  };
  int*   flag     = (int*)alloc(4);
  int*   deg      = (int*)alloc((size_t)n * 4);
  int*   cursor   = (int*)alloc((size_t)n * 4);
  int*   rowptr   = (int*)alloc(((size_t)n + 1) * 4);
  int*   partials = (int*)alloc(1024);
  int*   csr      = (int*)alloc((size_t)M * 4);
  float* hbuf     = (float*)alloc((size_t)n * HC * 4);
  float* asb      = (float*)alloc((size_t)n * 4 * 4);
  float* adb      = (float*)alloc((size_t)n * 4 * 4);
  float* hmid     = (float*)alloc((size_t)n * 64 * 4);
  float* out      = (float*)d_out;

  hipMemsetAsync(deg, 0, (size_t)n * 4, stream);
  k_detect<<<1, 64, 0, stream>>>(ei, flag);
  k_hist<<<(M + 255) / 256, 256, 0, stream>>>(ei, flag, deg, E_, n);
  k_scan_part<<<nb, 256, 0, stream>>>(deg, partials, n);
  k_scan_mid<<<1, 256, 0, stream>>>(partials, rowptr, nb, n);
  k_scan_final<<<nb, 256, 0, stream>>>(deg, partials, rowptr, cursor, n);
  k_scatter<<<(M + 255) / 256, 256, 0, stream>>>(ei, flag, cursor, csr, E_, n);

  dim3 ggrid((n + 127) / 128, 2);
  // layer 1
  k_gemm_fused<<<ggrid, 256, 0, stream>>>(x, W1, a_src1, a_dst1, hbuf, asb, adb, n, 128);
  k_agg<true><<<(n + 3) / 4, 256, 0, stream>>>(rowptr, csr, hbuf, asb, adb, b1, hmid, n);
  // layer 2
  k_gemm_fused<<<ggrid, 256, 0, stream>>>(hmid, W2, a_src2, a_dst2, hbuf, asb, adb, n, 64);
  k_agg<false><<<(n + 3) / 4, 256, 0, stream>>>(rowptr, csr, hbuf, asb, adb, b2, out, n);
}

// Round 9
// 526.046 us; speedup vs baseline: 1.2096x; 1.0097x over previous
//
#include <hip/hip_runtime.h>
#include <math.h>

#define NEG_SLOPE 0.2f
#define HC 256      // heads * per-head channels
#define CAPD 128    // LDS stash capacity per node (degree cap; fallback path)
#define SCAN_CHUNK 1024

static __device__ __forceinline__ int wave_sum_i(int v) {
#pragma unroll
  for (int off = 32; off; off >>= 1) v += __shfl_xor(v, off);
  return v;
}

// ---- detect int64 vs int32 edge_index: odd dwords all zero <=> int64 ----
__global__ void k_detect(const int* __restrict__ ei, int* __restrict__ flag) {
  int lane = threadIdx.x;
  int v = ei[2 * lane + 1];
#pragma unroll
  for (int off = 32; off; off >>= 1) v |= __shfl_xor(v, off);
  if (lane == 0) *flag = (v == 0) ? 1 : 0;
}

// ---- degree histogram over E edges + N self loops ----
__global__ void k_hist(const int* __restrict__ ei, const int* __restrict__ flag,
                       int* __restrict__ deg, int E_, int n) {
  int t = blockIdx.x * 256 + threadIdx.x;
  int M = E_ + n;
  if (t >= M) return;
  int is64 = *flag;
  int dst;
  if (t < E_) dst = is64 ? ei[2 * (E_ + t)] : ei[E_ + t];
  else dst = t - E_;
  atomicAdd(&deg[dst], 1);
}

// ---- 3-kernel scan: per-block partial sums ----
__global__ __launch_bounds__(256) void k_scan_part(const int* __restrict__ deg,
                                                   int* __restrict__ partials, int n) {
  __shared__ int red[4];
  int b = blockIdx.x, tid = threadIdx.x;
  int base = b * SCAN_CHUNK + tid * 4;
  int s = 0;
#pragma unroll
  for (int j = 0; j < 4; ++j) {
    int i = base + j;
    if (i < n) s += deg[i];
  }
  s = wave_sum_i(s);
  if ((tid & 63) == 0) red[tid >> 6] = s;
  __syncthreads();
  if (tid == 0) partials[b] = red[0] + red[1] + red[2] + red[3];
}

// ---- scan the (<=256) partials, in place -> exclusive offsets; rowptr[n]=total ----
__global__ void k_scan_mid(int* __restrict__ partials, int* __restrict__ rowptr,
                           int nb, int n) {
  __shared__ int buf[256];
  int tid = threadIdx.x;
  buf[tid] = (tid < nb) ? partials[tid] : 0;
  __syncthreads();
  if (tid == 0) {
    int run = 0;
    for (int i = 0; i < nb; ++i) {
      int v = buf[i];
      buf[i] = run;
      run += v;
    }
    rowptr[n] = run;
  }
  __syncthreads();
  if (tid < nb) partials[tid] = buf[tid];
}

// ---- block-local scan + global offset -> rowptr, cursor ----
__global__ __launch_bounds__(256) void k_scan_final(const int* __restrict__ deg,
                                                    const int* __restrict__ partials,
                                                    int* __restrict__ rowptr,
                                                    int* __restrict__ cursor, int n) {
  __shared__ int tsum[256];
  int b = blockIdx.x, tid = threadIdx.x;
  int base = b * SCAN_CHUNK + tid * 4;
  int v[4];
  int s = 0;
#pragma unroll
  for (int j = 0; j < 4; ++j) {
    int i = base + j;
    v[j] = (i < n) ? deg[i] : 0;
    s += v[j];
  }
  tsum[tid] = s;
  __syncthreads();
  for (int off = 1; off < 256; off <<= 1) {
    int t = (tid >= off) ? tsum[tid - off] : 0;
    __syncthreads();
    tsum[tid] += t;
    __syncthreads();
  }
  int run = partials[b] + ((tid == 0) ? 0 : tsum[tid - 1]);
#pragma unroll
  for (int j = 0; j < 4; ++j) {
    int i = base + j;
    if (i < n) {
      rowptr[i] = run;
      cursor[i] = run;
      run += v[j];
    }
  }
}

// ---- scatter src into CSR buckets ----
__global__ void k_scatter(const int* __restrict__ ei, const int* __restrict__ flag,
                          int* __restrict__ cursor, int* __restrict__ csr,
                          int E_, int n) {
  int t = blockIdx.x * 256 + threadIdx.x;
  int M = E_ + n;
  if (t >= M) return;
  int is64 = *flag;
  int src, dst;
  if (t < E_) {
    src = is64 ? ei[2 * t] : ei[t];
    dst = is64 ? ei[2 * (E_ + t)] : ei[E_ + t];
  } else {
    src = dst = t - E_;
  }
  int pos = atomicAdd(&cursor[dst], 1);
  csr[pos] = src;
}

// ---- fused GEMM: H[n,256] = A[n,K] @ W[256,K]^T ; per-head alpha dots fused ----
// 128x128 tile, 8x8 per thread. grid: (ceil(n/128), 2); blockIdx.y picks cols
// [128*by,128*by+128) = heads {2by, 2by+1}.
#define BK 32
__global__ __launch_bounds__(256, 2) void k_gemm_fused(
    const float* __restrict__ A, const float* __restrict__ W,
    const float* __restrict__ a_src, const float* __restrict__ a_dst,
    float* __restrict__ H, float* __restrict__ as_out, float* __restrict__ ad_out,
    int n, int K) {
  __shared__ float As[BK][132];
  __shared__ float Bs[BK][132];
  const int by = blockIdx.y;
  const int n0 = blockIdx.x * 128;
  const int tid = threadIdx.x;
  const int tx = tid & 15, ty = tid >> 4;
  float c[8][8];
#pragma unroll
  for (int i = 0; i < 8; ++i)
#pragma unroll
    for (int j = 0; j < 8; ++j) c[i][j] = 0.f;

  for (int k0 = 0; k0 < K; k0 += BK) {
#pragma unroll
    for (int l = 0; l < 4; ++l) {
      int f = tid + l * 256;           // 0..1023
      int m = f >> 3, kq = f & 7;      // m: row-in-tile, kq: k-quad
      int row = n0 + m;
      float4 a4 = make_float4(0.f, 0.f, 0.f, 0.f);
      if (row < n) a4 = *(const float4*)(A + (size_t)row * K + k0 + kq * 4);
      As[kq * 4 + 0][m] = a4.x; As[kq * 4 + 1][m] = a4.y;
      As[kq * 4 + 2][m] = a4.z; As[kq * 4 + 3][m] = a4.w;
      float4 b4 = *(const float4*)(W + (size_t)(by * 128 + m) * K + k0 + kq * 4);
      Bs[kq * 4 + 0][m] = b4.x; Bs[kq * 4 + 1][m] = b4.y;
      Bs[kq * 4 + 2][m] = b4.z; Bs[kq * 4 + 3][m] = b4.w;
    }
    __syncthreads();
#pragma unroll
    for (int k = 0; k < BK; ++k) {
      float4 a0 = *(const float4*)&As[k][ty * 8];
      float4 a1 = *(const float4*)&As[k][ty * 8 + 4];
      float4 b0 = *(const float4*)&Bs[k][tx * 8];
      float4 b1 = *(const float4*)&Bs[k][tx * 8 + 4];
      float a_[8] = {a0.x, a0.y, a0.z, a0.w, a1.x, a1.y, a1.z, a1.w};
      float b_[8] = {b0.x, b0.y, b0.z, b0.w, b1.x, b1.y, b1.z, b1.w};
#pragma unroll
      for (int i = 0; i < 8; ++i)
#pragma unroll
        for (int j = 0; j < 8; ++j) c[i][j] = fmaf(a_[i], b_[j], c[i][j]);
    }
    __syncthreads();
  }

  const int head = 2 * by + (tx >> 3);
  float asv[8], adv[8];
#pragma unroll
  for (int j = 0; j < 8; ++j) {
    asv[j] = a_src[head * 64 + (tx & 7) * 8 + j];
    adv[j] = a_dst[head * 64 + (tx & 7) * 8 + j];
  }
#pragma unroll
  for (int i = 0; i < 8; ++i) {
    int row = n0 + ty * 8 + i;
    if (row < n) {
      *(float4*)(H + (size_t)row * HC + by * 128 + tx * 8) =
          make_float4(c[i][0], c[i][1], c[i][2], c[i][3]);
      *(float4*)(H + (size_t)row * HC + by * 128 + tx * 8 + 4) =
          make_float4(c[i][4], c[i][5], c[i][6], c[i][7]);
      float ps = 0.f, pd = 0.f;
#pragma unroll
      for (int j = 0; j < 8; ++j) {
        ps = fmaf(c[i][j], asv[j], ps);
        pd = fmaf(c[i][j], adv[j], pd);
      }
#pragma unroll
      for (int off = 1; off < 8; off <<= 1) {
        ps += __shfl_xor(ps, off);
        pd += __shfl_xor(pd, off);
      }
      if ((tx & 7) == 0) {
        as_out[row * 4 + head] = ps;
        ad_out[row * 4 + head] = pd;
      }
    }
  }
}

// ---- per-destination softmax + aggregation; WAVE = node ----
// Pass B is unrolled x4: four independent dwordx4 gathers in flight per wave
// before any consuming FMA (MLP: cover L2/L3 latency with bytes in flight).
template <bool ELU>
__global__ __launch_bounds__(256) void k_agg(
    const int* __restrict__ rowptr, const int* __restrict__ csr,
    const float* __restrict__ h, const float* __restrict__ as,
    const float* __restrict__ ad, const float* __restrict__ bias,
    float* __restrict__ out, int n) {
  __shared__ int   sbuf[4][CAPD];
  __shared__ float wbuf[4][CAPD][5];   // [slot][edge][head(+pad)] — conflict-free
  const int slot = threadIdx.x >> 6;
  const int lane = threadIdx.x & 63;
  const int head = lane >> 4;
  const int li   = lane & 15;
  const int node = blockIdx.x * 4 + slot;
  if (node >= n) return;
  const int r0 = rowptr[node];
  const int d  = rowptr[node + 1] - r0;
  const float adh = ad[node * 4 + head];
  const bool stash = (d <= CAPD);

  // Pass A: leaky-relu scores + per-head max (16 lanes/head over edges)
  float m = -INFINITY;
  for (int i = li; i < d; i += 16) {
    int s = csr[r0 + i];
    float v = as[s * 4 + head] + adh;
    v = (v >= 0.f) ? v : NEG_SLOPE * v;
    if (stash) {
      wbuf[slot][i][head] = v;
      if (head == 0) sbuf[slot][i] = s;
    }
    m = fmaxf(m, v);
  }
#pragma unroll
  for (int off = 1; off < 16; off <<= 1) m = fmaxf(m, __shfl_xor(m, off));

  // Pass B: online denom + full-row weighted gather, 4 loads in flight
  float4 acc = make_float4(0.f, 0.f, 0.f, 0.f);
  float denom = 0.f;
  const float* hb = h + (size_t)head * 64 + li * 4;
  int e = 0;
  if (stash) {
    for (; e + 4 <= d; e += 4) {
      int s0 = sbuf[slot][e + 0];
      int s1 = sbuf[slot][e + 1];
      int s2 = sbuf[slot][e + 2];
      int s3 = sbuf[slot][e + 3];
      float4 h0 = *(const float4*)(hb + (size_t)s0 * HC);
      float4 h1 = *(const float4*)(hb + (size_t)s1 * HC);
      float4 h2 = *(const float4*)(hb + (size_t)s2 * HC);
      float4 h3 = *(const float4*)(hb + (size_t)s3 * HC);
      float w0 = __expf(wbuf[slot][e + 0][head] - m);
      float w1 = __expf(wbuf[slot][e + 1][head] - m);
      float w2 = __expf(wbuf[slot][e + 2][head] - m);
      float w3 = __expf(wbuf[slot][e + 3][head] - m);
      denom += (w0 + w1) + (w2 + w3);
      acc.x = fmaf(w0, h0.x, fmaf(w1, h1.x, fmaf(w2, h2.x, fmaf(w3, h3.x, acc.x))));
      acc.y = fmaf(w0, h0.y, fmaf(w1, h1.y, fmaf(w2, h2.y, fmaf(w3, h3.y, acc.y))));
      acc.z = fmaf(w0, h0.z, fmaf(w1, h1.z, fmaf(w2, h2.z, fmaf(w3, h3.z, acc.z))));
      acc.w = fmaf(w0, h0.w, fmaf(w1, h1.w, fmaf(w2, h2.w, fmaf(w3, h3.w, acc.w))));
    }
    for (; e < d; ++e) {
      int s = sbuf[slot][e];
      float4 hv = *(const float4*)(hb + (size_t)s * HC);
      float w = __expf(wbuf[slot][e][head] - m);
      denom += w;
      acc.x = fmaf(w, hv.x, acc.x);
      acc.y = fmaf(w, hv.y, acc.y);
      acc.z = fmaf(w, hv.z, acc.z);
      acc.w = fmaf(w, hv.w, acc.w);
    }
  } else {
    for (; e + 4 <= d; e += 4) {
      int s0 = csr[r0 + e + 0];
      int s1 = csr[r0 + e + 1];
      int s2 = csr[r0 + e + 2];
      int s3 = csr[r0 + e + 3];
      float4 h0 = *(const float4*)(hb + (size_t)s0 * HC);
      float4 h1 = *(const float4*)(hb + (size_t)s1 * HC);
      float4 h2 = *(const float4*)(hb + (size_t)s2 * HC);
      float4 h3 = *(const float4*)(hb + (size_t)s3 * HC);
      float v0 = as[s0 * 4 + head] + adh; v0 = (v0 >= 0.f) ? v0 : NEG_SLOPE * v0;
      float v1 = as[s1 * 4 + head] + adh; v1 = (v1 >= 0.f) ? v1 : NEG_SLOPE * v1;
      float v2 = as[s2 * 4 + head] + adh; v2 = (v2 >= 0.f) ? v2 : NEG_SLOPE * v2;
      float v3 = as[s3 * 4 + head] + adh; v3 = (v3 >= 0.f) ? v3 : NEG_SLOPE * v3;
      float w0 = __expf(v0 - m), w1 = __expf(v1 - m);
      float w2 = __expf(v2 - m), w3 = __expf(v3 - m);
      denom += (w0 + w1) + (w2 + w3);
      acc.x = fmaf(w0, h0.x, fmaf(w1, h1.x, fmaf(w2, h2.x, fmaf(w3, h3.x, acc.x))));
      acc.y = fmaf(w0, h0.y, fmaf(w1, h1.y, fmaf(w2, h2.y, fmaf(w3, h3.y, acc.y))));
      acc.z = fmaf(w0, h0.z, fmaf(w1, h1.z, fmaf(w2, h2.z, fmaf(w3, h3.z, acc.z))));
      acc.w = fmaf(w0, h0.w, fmaf(w1, h1.w, fmaf(w2, h2.w, fmaf(w3, h3.w, acc.w))));
    }
    for (; e < d; ++e) {
      int s = csr[r0 + e];
      float4 hv = *(const float4*)(hb + (size_t)s * HC);
      float v = as[s * 4 + head] + adh;
      v = (v >= 0.f) ? v : NEG_SLOPE * v;
      float w = __expf(v - m);
      denom += w;
      acc.x = fmaf(w, hv.x, acc.x);
      acc.y = fmaf(w, hv.y, acc.y);
      acc.z = fmaf(w, hv.z, acc.z);
      acc.w = fmaf(w, hv.w, acc.w);
    }
  }
  const float inv = 1.f / (denom + 1e-16f);
  acc.x *= inv; acc.y *= inv; acc.z *= inv; acc.w *= inv;

  // head-mean across the 4 lane groups
#pragma unroll
  for (int off = 16; off < 64; off <<= 1) {
    acc.x += __shfl_xor(acc.x, off);
    acc.y += __shfl_xor(acc.y, off);
    acc.z += __shfl_xor(acc.z, off);
    acc.w += __shfl_xor(acc.w, off);
  }
  if (head == 0) {
    float4 b4 = *(const float4*)(bias + li * 4);
    float4 o;
    o.x = 0.25f * acc.x + b4.x;
    o.y = 0.25f * acc.y + b4.y;
    o.z = 0.25f * acc.z + b4.z;
    o.w = 0.25f * acc.w + b4.w;
    if (ELU) {
      o.x = (o.x > 0.f) ? o.x : (__expf(o.x) - 1.f);
      o.y = (o.y > 0.f) ? o.y : (__expf(o.y) - 1.f);
      o.z = (o.z > 0.f) ? o.z : (__expf(o.z) - 1.f);
      o.w = (o.w > 0.f) ? o.w : (__expf(o.w) - 1.f);
    }
    *(float4*)(out + (size_t)node * 64 + li * 4) = o;
  }
}

extern "C" void kernel_launch(void* const* d_in, const int* in_sizes, int n_in,
                              void* d_out, int out_size, void* d_ws, size_t ws_size,
                              hipStream_t stream) {
  const float* x      = (const float*)d_in[0];
  const int*   ei     = (const int*)d_in[1];
  const float* W1     = (const float*)d_in[2];
  const float* a_src1 = (const float*)d_in[3];
  const float* a_dst1 = (const float*)d_in[4];
  const float* b1     = (const float*)d_in[5];
  const float* W2     = (const float*)d_in[6];
  const float* a_src2 = (const float*)d_in[7];
  const float* a_dst2 = (const float*)d_in[8];
  const float* b2     = (const float*)d_in[9];

  const int n  = in_sizes[0] / 128;   // 50000
  const int E_ = in_sizes[1] / 2;     // 800000
  const int M  = E_ + n;
  const int nb = (n + SCAN_CHUNK - 1) / SCAN_CHUNK;

  char* p = (char*)d_ws;
  auto alloc = [&](size_t bytes) -> void* {
    void* r = (void*)p;
    p += (bytes + 255) & ~(size_t)255;
    return r;
  };
  int*   flag     = (int*)alloc(4);
  int*   deg      = (int*)alloc((size_t)n * 4);
  int*   cursor   = (int*)alloc((size_t)n * 4);
  int*   rowptr   = (int*)alloc(((size_t)n + 1) * 4);
  int*   partials = (int*)alloc(1024);
  int*   csr      = (int*)alloc((size_t)M * 4);
  float* hbuf     = (float*)alloc((size_t)n * HC * 4);
  float* asb      = (float*)alloc((size_t)n * 4 * 4);
  float* adb      = (float*)alloc((size_t)n * 4 * 4);
  float* hmid     = (float*)alloc((size_t)n * 64 * 4);
  float* out      = (float*)d_out;

  hipMemsetAsync(deg, 0, (size_t)n * 4, stream);
  k_detect<<<1, 64, 0, stream>>>(ei, flag);
  k_hist<<<(M + 255) / 256, 256, 0, stream>>>(ei, flag, deg, E_, n);
  k_scan_part<<<nb, 256, 0, stream>>>(deg, partials, n);
  k_scan_mid<<<1, 256, 0, stream>>>(partials, rowptr, nb, n);
  k_scan_final<<<nb, 256, 0, stream>>>(deg, partials, rowptr, cursor, n);
  k_scatter<<<(M + 255) / 256, 256, 0, stream>>>(ei, flag, cursor, csr, E_, n);

  dim3 ggrid((n + 127) / 128, 2);
  // layer 1
  k_gemm_fused<<<ggrid, 256, 0, stream>>>(x, W1, a_src1, a_dst1, hbuf, asb, adb, n, 128);
  k_agg<true><<<(n + 3) / 4, 256, 0, stream>>>(rowptr, csr, hbuf, asb, adb, b1, hmid, n);
  // layer 2
  k_gemm_fused<<<ggrid, 256, 0, stream>>>(hmid, W2, a_src2, a_dst2, hbuf, asb, adb, n, 64);
  k_agg<false><<<(n + 3) / 4, 256, 0, stream>>>(rowptr, csr, hbuf, asb, adb, b2, out, n);
}